// Round 1
// baseline (3671.064 us; speedup 1.0000x reference)
//
#include <hip/hip_runtime.h>
#include <hip/hip_bf16.h>

// ---------------------------------------------------------------------------
// PointerGenerator forward, MI355X.
// Key identity: softmax_l(enc_att + const_b) == softmax_l(enc_att)  =>
// attention weights / context / copy-dist are decoder-step-invariant.
// Decoder reduces to an LSTM scan + one big parallel vocab GEMM.
// ---------------------------------------------------------------------------

#define DEVINL __device__ __forceinline__

typedef _Float16 f16;
typedef _Float16 f16x2 __attribute__((ext_vector_type(2)));
typedef _Float16 f16x8 __attribute__((ext_vector_type(8)));
typedef short    s16x8 __attribute__((ext_vector_type(8)));
typedef float    f32x4 __attribute__((ext_vector_type(4)));

DEVINL float dot2f(unsigned int a, unsigned int b, float acc) {
#if __has_builtin(__builtin_amdgcn_fdot2)
  return __builtin_amdgcn_fdot2(__builtin_bit_cast(f16x2, a),
                                __builtin_bit_cast(f16x2, b), acc, false);
#else
  f16x2 x = __builtin_bit_cast(f16x2, a);
  f16x2 y = __builtin_bit_cast(f16x2, b);
  return acc + (float)x[0] * (float)y[0] + (float)x[1] * (float)y[1];
#endif
}

DEVINL float sigm(float x) { return 1.0f / (1.0f + __expf(-x)); }
DEVINL float tanh_f(float x) {
  float e = __expf(2.0f * x);
  return (e - 1.0f) / (e + 1.0f);
}
DEVINL unsigned int pack2(float a, float b) {
  f16x2 p; p[0] = (f16)a; p[1] = (f16)b;
  return __builtin_bit_cast(unsigned int, p);
}

// ---------------------------------------------------------------------------
// Weight packing
// ---------------------------------------------------------------------------

// Whh (1024 x 256 fp32) -> Wp[k2b][j] uint4, k2b in [0,32) covers k=8*k2b..+7
__global__ __launch_bounds__(256) void k_pack_whh(const float* __restrict__ W,
                                                  uint4* __restrict__ dst) {
  int id = blockIdx.x * 256 + threadIdx.x;       // 32768
  int k2b = id >> 10, j = id & 1023;
  const float* s = W + (size_t)j * 256 + k2b * 8;
  uint4 u;
  u.x = pack2(s[0], s[1]); u.y = pack2(s[2], s[3]);
  u.z = pack2(s[4], s[5]); u.w = pack2(s[6], s[7]);
  dst[k2b * 1024 + j] = u;
}

// Wih (1024 x ldk fp32, first 128 cols) -> W2[j][k2] uint (half2), k2<64
__global__ __launch_bounds__(256) void k_pack_wih(const float* __restrict__ W,
                                                  unsigned int* __restrict__ dst,
                                                  int ldk) {
  int id = blockIdx.x * 256 + threadIdx.x;       // 65536
  int j = id >> 6, k2 = id & 63;
  dst[j * 64 + k2] = pack2(W[(size_t)j * ldk + 2 * k2],
                           W[(size_t)j * ldk + 2 * k2 + 1]);
}

__global__ __launch_bounds__(256) void k_pack_vpw(const float* __restrict__ W,
                                                  __hip_bfloat16* __restrict__ dst) {
  size_t id = (size_t)blockIdx.x * 256 + threadIdx.x;   // 24,576,000
  dst[id] = __float2bfloat16(W[id]);
}

// ---------------------------------------------------------------------------
// Encoder input projection: X[row][b][j] = emb[b][l] @ Wih.T + bias, f16 out.
// One block per l (256 thr). rev=1 stores to row 511-l (backward direction).
// ---------------------------------------------------------------------------
__global__ __launch_bounds__(256) void k_encproj(
    const int* __restrict__ source, const float* __restrict__ emb,
    const unsigned int* __restrict__ W2, const float* __restrict__ bias,
    f16* __restrict__ X, int rev) {
  int l = blockIdx.x;
  int tid = threadIdx.x;
  __shared__ int toks[32];
  __shared__ unsigned int e2[32 * 66];    // padded rows: bank spread
  if (tid < 32) toks[tid] = source[tid * 512 + l];
  __syncthreads();
  {
    int row = tid >> 3;
    int k2b = (tid & 7) * 8;
    const float* er = emb + (size_t)toks[row] * 128 + k2b * 2;
#pragma unroll
    for (int i = 0; i < 8; ++i)
      e2[row * 66 + k2b + i] = pack2(er[2 * i], er[2 * i + 1]);
  }
  __syncthreads();
  int jg = tid >> 3;        // 0..31 -> j-octet
  int bq = (tid & 7) * 4;   // batch quad base
  int orow = rev ? (511 - l) : l;
  for (int jt = 0; jt < 4; ++jt) {
    int j0 = jt * 256 + jg * 8;
    float acc[8][4];
#pragma unroll
    for (int jj = 0; jj < 8; ++jj) {
      float bv = bias[j0 + jj];
#pragma unroll
      for (int bb = 0; bb < 4; ++bb) acc[jj][bb] = bv;
    }
    for (int kp = 0; kp < 32; ++kp) {
      uint2 w[8], e[4];
#pragma unroll
      for (int jj = 0; jj < 8; ++jj)
        w[jj] = *(const uint2*)(W2 + (size_t)(j0 + jj) * 64 + kp * 2);
#pragma unroll
      for (int bb = 0; bb < 4; ++bb)
        e[bb] = *(const uint2*)(e2 + (bq + bb) * 66 + kp * 2);
#pragma unroll
      for (int jj = 0; jj < 8; ++jj)
#pragma unroll
        for (int bb = 0; bb < 4; ++bb) {
          acc[jj][bb] = dot2f(e[bb].x, w[jj].x, acc[jj][bb]);
          acc[jj][bb] = dot2f(e[bb].y, w[jj].y, acc[jj][bb]);
        }
    }
#pragma unroll
    for (int bb = 0; bb < 4; ++bb) {
      f16x8 v;
#pragma unroll
      for (int jj = 0; jj < 8; ++jj) v[jj] = (f16)acc[jj][bb];
      *(f16x8*)(X + ((size_t)orow * 32 + bq + bb) * 1024 + j0) = v;
    }
  }
}

// ---------------------------------------------------------------------------
// Decoder input projection (emb part only; context part comes via cprj which
// already includes dec_b). Also emits pemb[t][b] = emb_t . pg_W[768:896].
// ---------------------------------------------------------------------------
__global__ __launch_bounds__(256) void k_decproj(
    const int* __restrict__ target, const float* __restrict__ emb,
    const unsigned int* __restrict__ W2, const float* __restrict__ cprj,
    const float* __restrict__ pgW, f16* __restrict__ X,
    float* __restrict__ pemb) {
  int t = blockIdx.x;
  int tid = threadIdx.x;
  __shared__ int toks[32];
  __shared__ unsigned int e2[32 * 66];
  if (tid < 32) toks[tid] = (t == 0) ? 0 : target[tid * 64 + t - 1];
  __syncthreads();
  {
    int row = tid >> 3;
    int k2b = (tid & 7) * 8;
    const float* er = emb + (size_t)toks[row] * 128 + k2b * 2;
#pragma unroll
    for (int i = 0; i < 8; ++i)
      e2[row * 66 + k2b + i] = pack2(er[2 * i], er[2 * i + 1]);
  }
  __syncthreads();
  if (tid < 32) {
    float s = 0.f;
    for (int k2 = 0; k2 < 64; ++k2) {
      f16x2 p = __builtin_bit_cast(f16x2, e2[tid * 66 + k2]);
      s += (float)p[0] * pgW[768 + 2 * k2] + (float)p[1] * pgW[768 + 2 * k2 + 1];
    }
    pemb[t * 32 + tid] = s;
  }
  int jg = tid >> 3;
  int bq = (tid & 7) * 4;
  for (int jt = 0; jt < 4; ++jt) {
    int j0 = jt * 256 + jg * 8;
    float acc[8][4];
#pragma unroll
    for (int jj = 0; jj < 8; ++jj)
#pragma unroll
      for (int bb = 0; bb < 4; ++bb)
        acc[jj][bb] = cprj[(size_t)(bq + bb) * 1024 + j0 + jj];
    for (int kp = 0; kp < 32; ++kp) {
      uint2 w[8], e[4];
#pragma unroll
      for (int jj = 0; jj < 8; ++jj)
        w[jj] = *(const uint2*)(W2 + (size_t)(j0 + jj) * 64 + kp * 2);
#pragma unroll
      for (int bb = 0; bb < 4; ++bb)
        e[bb] = *(const uint2*)(e2 + (bq + bb) * 66 + kp * 2);
#pragma unroll
      for (int jj = 0; jj < 8; ++jj)
#pragma unroll
        for (int bb = 0; bb < 4; ++bb) {
          acc[jj][bb] = dot2f(e[bb].x, w[jj].x, acc[jj][bb]);
          acc[jj][bb] = dot2f(e[bb].y, w[jj].y, acc[jj][bb]);
        }
    }
#pragma unroll
    for (int bb = 0; bb < 4; ++bb) {
      f16x8 v;
#pragma unroll
      for (int jj = 0; jj < 8; ++jj) v[jj] = (f16)acc[jj][bb];
      *(f16x8*)(X + ((size_t)t * 32 + bq + bb) * 1024 + j0) = v;
    }
  }
}

// ---------------------------------------------------------------------------
// LSTM scan. 512 threads, 2 batches per block. mode 0: encoder (grid 32,
// dir = bid>>4, fw writes enc_out[:, :, 0:256] + final c; bw writes
// enc_out[:, 511-t, 256:512]). mode 2: decoder (grid 16, out = h_all,
// init from enc_out[b][511][0:256] and cf).
// gemv: thread owns gate cols j0=tid, j1=tid+512 for both batches, f16 dot2.
// ---------------------------------------------------------------------------
__global__ __launch_bounds__(512) void k_scan(
    const uint4* __restrict__ Wp0, const f16* __restrict__ X0,
    float* __restrict__ out, float* __restrict__ cf,
    const float* __restrict__ hinit, int mode, int nsteps) {
  int bid = blockIdx.x;
  int dir  = (mode == 2) ? 0 : (bid >> 4);
  int pair = (mode == 2) ? bid : (bid & 15);
  int isbw = (mode != 2) && (dir == 1);
  int isdec = (mode == 2);
  const uint4* Wp = Wp0 + (size_t)dir * 32768;
  const f16* X = X0 + (size_t)dir * 16777216;
  int tid = threadIdx.x;
  int b0 = pair * 2;
  __shared__ __align__(16) f16 hh[2][256];
  __shared__ float gates[2][1024];
  int bl = tid >> 8, jh = tid & 255;
  int bg = b0 + bl;
  float c_reg;
  if (isdec) {
    c_reg = cf[bg * 256 + jh];
    hh[bl][jh] = (f16)hinit[((size_t)bg * 512 + 511) * 512 + jh];
  } else {
    c_reg = 0.f;
    hh[bl][jh] = (f16)0.f;
  }
  __syncthreads();
  int j0 = tid, j1 = tid + 512;
  for (int t = 0; t < nsteps; ++t) {
    const f16* x0 = X + ((size_t)t * 32 + b0) * 1024;
    const f16* x1 = x0 + 1024;
    float a00 = (float)x0[j0];
    float a01 = (float)x0[j1];
    float a10 = (float)x1[j0];
    float a11 = (float)x1[j1];
    const uint4* h0p = (const uint4*)hh[0];
    const uint4* h1p = (const uint4*)hh[1];
#pragma unroll 4
    for (int k = 0; k < 32; ++k) {
      uint4 w0 = Wp[(k << 10) + j0];
      uint4 w1 = Wp[(k << 10) + j1];
      uint4 h0 = h0p[k];
      uint4 h1 = h1p[k];
      a00 = dot2f(h0.x, w0.x, a00); a01 = dot2f(h0.x, w1.x, a01);
      a10 = dot2f(h1.x, w0.x, a10); a11 = dot2f(h1.x, w1.x, a11);
      a00 = dot2f(h0.y, w0.y, a00); a01 = dot2f(h0.y, w1.y, a01);
      a10 = dot2f(h1.y, w0.y, a10); a11 = dot2f(h1.y, w1.y, a11);
      a00 = dot2f(h0.z, w0.z, a00); a01 = dot2f(h0.z, w1.z, a01);
      a10 = dot2f(h1.z, w0.z, a10); a11 = dot2f(h1.z, w1.z, a11);
      a00 = dot2f(h0.w, w0.w, a00); a01 = dot2f(h0.w, w1.w, a01);
      a10 = dot2f(h1.w, w0.w, a10); a11 = dot2f(h1.w, w1.w, a11);
    }
    gates[0][j0] = a00; gates[0][j1] = a01;
    gates[1][j0] = a10; gates[1][j1] = a11;
    __syncthreads();
    float gi = gates[bl][jh];
    float gf_ = gates[bl][256 + jh];
    float gg = gates[bl][512 + jh];
    float go = gates[bl][768 + jh];
    c_reg = sigm(gf_) * c_reg + sigm(gi) * tanh_f(gg);
    float hv = sigm(go) * tanh_f(c_reg);
    hh[bl][jh] = (f16)hv;
    if (isdec)
      out[((size_t)t * 32 + bg) * 256 + jh] = hv;
    else if (isbw)
      out[((size_t)bg * 512 + (511 - t)) * 512 + 256 + jh] = hv;
    else
      out[((size_t)bg * 512 + t) * 512 + jh] = hv;
    __syncthreads();
  }
  if (!isdec && dir == 0) cf[bg * 256 + jh] = c_reg;
}

// ---------------------------------------------------------------------------
// Attention weights (step-invariant!), context, copy scatter, pctx.
// One block per batch, 512 threads (= L).
// ---------------------------------------------------------------------------
__global__ __launch_bounds__(512) void k_attention(
    const float* __restrict__ enc_out, const float* __restrict__ attn_w,
    const float* __restrict__ pgW, const int* __restrict__ source,
    float* __restrict__ aw_out, float* __restrict__ ctx_out,
    float* __restrict__ pctx, float* __restrict__ copyb) {
  int b = blockIdx.x, tid = threadIdx.x;
  __shared__ float red[512];
  __shared__ float awl[512];
  const float4* row = (const float4*)(enc_out + ((size_t)b * 512 + tid) * 512);
  const float4* wv = (const float4*)attn_w;   // wa_enc = attn_w[0:512]
  float s = 0.f;
  for (int i = 0; i < 128; ++i) {
    float4 r = row[i], w = wv[i];
    s += r.x * w.x + r.y * w.y + r.z * w.z + r.w * w.w;
  }
  red[tid] = s; __syncthreads();
  for (int off = 256; off > 0; off >>= 1) {
    if (tid < off) red[tid] = fmaxf(red[tid], red[tid + off]);
    __syncthreads();
  }
  float m = red[0]; __syncthreads();
  float e = __expf(s - m);
  red[tid] = e; __syncthreads();
  for (int off = 256; off > 0; off >>= 1) {
    if (tid < off) red[tid] += red[tid + off];
    __syncthreads();
  }
  float a = e / red[0];
  __syncthreads();
  awl[tid] = a;
  aw_out[b * 512 + tid] = a;
  atomicAdd(&copyb[(size_t)b * 32000 + source[b * 512 + tid]], a);
  __syncthreads();
  // context: thread = feature index e (512)
  float c = 0.f;
  const float* col = enc_out + (size_t)b * 512 * 512 + tid;
  for (int ll = 0; ll < 512; ++ll) c += awl[ll] * col[(size_t)ll * 512];
  ctx_out[b * 512 + tid] = c;
  red[tid] = c * pgW[256 + tid];
  __syncthreads();
  for (int off = 256; off > 0; off >>= 1) {
    if (tid < off) red[tid] += red[tid + off];
    __syncthreads();
  }
  if (tid == 0) pctx[b] = red[0];
}

// ctxproj[b][j] = dec_b[j] + context[b] . dec_Wih[j][128:640]
__global__ __launch_bounds__(256) void k_ctxproj(
    const float* __restrict__ ctx, const float* __restrict__ dWih,
    const float* __restrict__ db, float* __restrict__ cprj) {
  int b = blockIdx.x, tid = threadIdx.x;
  __shared__ float cs[512];
  cs[tid] = ctx[b * 512 + tid];
  cs[tid + 256] = ctx[b * 512 + 256 + tid];
  __syncthreads();
  const float4* c4 = (const float4*)cs;
  for (int q = 0; q < 4; ++q) {
    int j = q * 256 + tid;
    const float4* wr = (const float4*)(dWih + (size_t)j * 640 + 128);
    float s = db[j];
    for (int i = 0; i < 128; ++i) {
      float4 w = wr[i]; float4 c = c4[i];
      s += w.x * c.x + w.y * c.y + w.z * c.z + w.w * c.w;
    }
    cprj[b * 1024 + j] = s;
  }
}

// p_gen + assemble gen_feat rows (bf16) for the vocab GEMM.
__global__ __launch_bounds__(256) void k_pgen_gf(
    const float* __restrict__ h_all, const float* __restrict__ ctx,
    const float* __restrict__ pgW, const float* __restrict__ pgb,
    const float* __restrict__ pctx, const float* __restrict__ pemb,
    float* __restrict__ pgen, __hip_bfloat16* __restrict__ gf) {
  int r = blockIdx.x, tid = threadIdx.x;   // r = t*32 + b
  int b = r & 31;
  float h = h_all[(size_t)r * 256 + tid];
  gf[(size_t)r * 768 + tid] = __float2bfloat16(h);
  float c0 = ctx[b * 512 + tid], c1 = ctx[b * 512 + 256 + tid];
  gf[(size_t)r * 768 + 256 + tid] = __float2bfloat16(c0);
  gf[(size_t)r * 768 + 512 + tid] = __float2bfloat16(c1);
  __shared__ float red[256];
  red[tid] = h * pgW[tid];
  __syncthreads();
  for (int off = 128; off > 0; off >>= 1) {
    if (tid < off) red[tid] += red[tid + off];
    __syncthreads();
  }
  if (tid == 0) pgen[r] = sigm(red[0] + pctx[b] + pemb[r] + pgb[0]);
}

// ---------------------------------------------------------------------------
// Vocab logits GEMM: (2048 x 768) bf16 @ (32000 x 768)^T bf16 -> fp32 logits
// straight into d_out at [b][t][v]. 128x128 tile, 4 waves, 16x16x32 MFMA.
// ---------------------------------------------------------------------------
__global__ __launch_bounds__(256) void k_logits(
    const __hip_bfloat16* __restrict__ A, const __hip_bfloat16* __restrict__ B,
    const float* __restrict__ vpb, float* __restrict__ out) {
  __shared__ short As[128 * 40];   // pitch 40 halves: bank spread, 16B aligned
  __shared__ short Bs[128 * 40];
  int tid = threadIdx.x;
  int bn = blockIdx.x, bm = blockIdx.y;
  int wave = tid >> 6, lane = tid & 63;
  int q = lane >> 4, m = lane & 15;
  f32x4 acc[2][8];
#pragma unroll
  for (int i = 0; i < 2; ++i)
#pragma unroll
    for (int j = 0; j < 8; ++j)
      acc[i][j] = (f32x4){0.f, 0.f, 0.f, 0.f};
  const short* Ag = (const short*)A + (size_t)(bm * 128) * 768;
  const short* Bg = (const short*)B + (size_t)(bn * 128) * 768;
  int lrow = tid >> 2;
  int lseg = (tid & 3) * 8;
  for (int kc = 0; kc < 768; kc += 32) {
    __syncthreads();
    *(s16x8*)&As[lrow * 40 + lseg] = *(const s16x8*)(Ag + (size_t)lrow * 768 + kc + lseg);
    *(s16x8*)&As[(lrow + 64) * 40 + lseg] = *(const s16x8*)(Ag + (size_t)(lrow + 64) * 768 + kc + lseg);
    *(s16x8*)&Bs[lrow * 40 + lseg] = *(const s16x8*)(Bg + (size_t)lrow * 768 + kc + lseg);
    *(s16x8*)&Bs[(lrow + 64) * 40 + lseg] = *(const s16x8*)(Bg + (size_t)(lrow + 64) * 768 + kc + lseg);
    __syncthreads();
    s16x8 a0 = *(const s16x8*)&As[(wave * 32 + m) * 40 + q * 8];
    s16x8 a1 = *(const s16x8*)&As[(wave * 32 + 16 + m) * 40 + q * 8];
#pragma unroll
    for (int nb = 0; nb < 8; ++nb) {
      s16x8 bf = *(const s16x8*)&Bs[(nb * 16 + m) * 40 + q * 8];
      acc[0][nb] = __builtin_amdgcn_mfma_f32_16x16x32_bf16(a0, bf, acc[0][nb], 0, 0, 0);
      acc[1][nb] = __builtin_amdgcn_mfma_f32_16x16x32_bf16(a1, bf, acc[1][nb], 0, 0, 0);
    }
  }
  // epilogue: D row=(q*4+reg) in M, col=lane&15 in N
#pragma unroll
  for (int mb = 0; mb < 2; ++mb)
#pragma unroll
    for (int nb = 0; nb < 8; ++nb) {
      int v = bn * 128 + nb * 16 + m;
      float vb = vpb[v];
#pragma unroll
      for (int rg = 0; rg < 4; ++rg) {
        int R = bm * 128 + wave * 32 + mb * 16 + q * 4 + rg;   // r = t*32+b
        int bb = R & 31, tt = R >> 5;
        out[((size_t)bb * 64 + tt) * 32000 + v] = acc[mb][nb][rg] + vb;
      }
    }
}

// per-row (b*64+t) inverse sum of exp(logit)
__global__ __launch_bounds__(256) void k_rowsum(const float* __restrict__ out,
                                                float* __restrict__ invs) {
  int row = blockIdx.x, tid = threadIdx.x;
  const float* r = out + (size_t)row * 32000;
  float s = 0.f;
  for (int i = tid; i < 32000; i += 256) s += __expf(r[i]);
  __shared__ float red[256];
  red[tid] = s; __syncthreads();
  for (int off = 128; off > 0; off >>= 1) {
    if (tid < off) red[tid] += red[tid + off];
    __syncthreads();
  }
  if (tid == 0) invs[row] = 1.0f / red[0];
}

// final[b][t][v] = pg*softmax + (1-pg)*copy  (in place over logits)
__global__ __launch_bounds__(256) void k_final(float* __restrict__ out,
                                               const float* __restrict__ invs,
                                               const float* __restrict__ pgen,
                                               const float* __restrict__ copyb) {
  int row = blockIdx.x;              // b*64 + t
  int b = row >> 6, t = row & 63;
  float pg = pgen[t * 32 + b];
  float inv = invs[row];
  float* r = out + (size_t)row * 32000;
  const float* cp = copyb + (size_t)b * 32000;
  for (int i = threadIdx.x; i < 32000; i += 256)
    r[i] = pg * __expf(r[i]) * inv + (1.f - pg) * cp[i];
}

// ---------------------------------------------------------------------------
extern "C" void kernel_launch(void* const* d_in, const int* in_sizes, int n_in,
                              void* d_out, int out_size, void* d_ws, size_t ws_size,
                              hipStream_t stream) {
  (void)in_sizes; (void)n_in; (void)out_size;
  const int*   source = (const int*)d_in[0];
  const int*   target = (const int*)d_in[1];
  const float* embedding = (const float*)d_in[2];
  const float* Wih_f = (const float*)d_in[3];
  const float* Whh_f = (const float*)d_in[4];
  const float* b_f   = (const float*)d_in[5];
  const float* Wih_b = (const float*)d_in[6];
  const float* Whh_b = (const float*)d_in[7];
  const float* b_b   = (const float*)d_in[8];
  const float* dWih  = (const float*)d_in[9];
  const float* dWhh  = (const float*)d_in[10];
  const float* db    = (const float*)d_in[11];
  const float* attn_w = (const float*)d_in[12];
  // d_in[13] attn_b, d_in[14] dp_W, d_in[15] dp_b: dead (softmax shift-invariance)
  const float* vpW = (const float*)d_in[16];
  const float* vpb = (const float*)d_in[17];
  const float* pgW = (const float*)d_in[18];
  const float* pgb = (const float*)d_in[19];

  constexpr size_t OFF_WP   = 0;                          // 3 dirs * 512KB
  constexpr size_t OFF_WIH2 = OFF_WP + 3ull * 32768 * 16;
  constexpr size_t OFF_VP16 = OFF_WIH2 + 3ull * 65536 * 4;
  constexpr size_t OFF_XENC = OFF_VP16 + 24576000ull * 2;
  constexpr size_t OFF_XD   = OFF_XENC + 2ull * 16777216 * 2;
  constexpr size_t OFF_ENCO = OFF_XD + 2097152ull * 2;
  constexpr size_t OFF_CF   = OFF_ENCO + 8388608ull * 4;
  constexpr size_t OFF_AW   = OFF_CF + 32768;
  constexpr size_t OFF_CTX  = OFF_AW + 65536;
  constexpr size_t OFF_CPRJ = OFF_CTX + 65536;
  constexpr size_t OFF_PCTX = OFF_CPRJ + 131072;
  constexpr size_t OFF_PEMB = OFF_PCTX + 128;
  constexpr size_t OFF_PGEN = OFF_PEMB + 8192;
  constexpr size_t OFF_HALL = OFF_PGEN + 8192;
  constexpr size_t OFF_GF   = OFF_HALL + 2097152;
  constexpr size_t OFF_COPY = OFF_GF + 3145728;
  constexpr size_t OFF_INVS = OFF_COPY + 4096000;
  constexpr size_t WS_NEED  = OFF_INVS + 8192;
  if (ws_size < WS_NEED) return;   // workspace too small; fail visibly via absmax

  char* ws = (char*)d_ws;
  uint4* wp             = (uint4*)(ws + OFF_WP);
  unsigned int* wih2f   = (unsigned int*)(ws + OFF_WIH2);
  unsigned int* wih2b   = wih2f + 65536;
  unsigned int* wih2d   = wih2f + 131072;
  __hip_bfloat16* vp16  = (__hip_bfloat16*)(ws + OFF_VP16);
  f16* Xenc             = (f16*)(ws + OFF_XENC);
  f16* Xd               = (f16*)(ws + OFF_XD);
  float* enc_out        = (float*)(ws + OFF_ENCO);
  float* cf             = (float*)(ws + OFF_CF);
  float* aw             = (float*)(ws + OFF_AW);
  float* ctx            = (float*)(ws + OFF_CTX);
  float* cprj           = (float*)(ws + OFF_CPRJ);
  float* pctx           = (float*)(ws + OFF_PCTX);
  float* pemb           = (float*)(ws + OFF_PEMB);
  float* pgen           = (float*)(ws + OFF_PGEN);
  float* h_all          = (float*)(ws + OFF_HALL);
  __hip_bfloat16* gf    = (__hip_bfloat16*)(ws + OFF_GF);
  float* copyb          = (float*)(ws + OFF_COPY);
  float* invs           = (float*)(ws + OFF_INVS);
  float* outp           = (float*)d_out;

  hipMemsetAsync(copyb, 0, 32ull * 32000 * 4, stream);

  k_pack_whh<<<128, 256, 0, stream>>>(Whh_f, wp);
  k_pack_whh<<<128, 256, 0, stream>>>(Whh_b, wp + 32768);
  k_pack_whh<<<128, 256, 0, stream>>>(dWhh,  wp + 65536);
  k_pack_wih<<<256, 256, 0, stream>>>(Wih_f, wih2f, 128);
  k_pack_wih<<<256, 256, 0, stream>>>(Wih_b, wih2b, 128);
  k_pack_wih<<<256, 256, 0, stream>>>(dWih,  wih2d, 640);
  k_pack_vpw<<<96000, 256, 0, stream>>>(vpW, vp16);

  k_encproj<<<512, 256, 0, stream>>>(source, embedding, wih2f, b_f, Xenc, 0);
  k_encproj<<<512, 256, 0, stream>>>(source, embedding, wih2b, b_b,
                                     Xenc + 16777216, 1);
  k_scan<<<32, 512, 0, stream>>>(wp, Xenc, enc_out, cf, nullptr, 0, 512);
  k_attention<<<32, 512, 0, stream>>>(enc_out, attn_w, pgW, source, aw, ctx,
                                      pctx, copyb);
  k_ctxproj<<<32, 256, 0, stream>>>(ctx, dWih, db, cprj);
  k_decproj<<<64, 256, 0, stream>>>(target, embedding, wih2d, cprj, pgW, Xd,
                                    pemb);
  k_scan<<<16, 512, 0, stream>>>(wp + 65536, Xd, h_all, cf, enc_out, 2, 64);
  k_pgen_gf<<<2048, 256, 0, stream>>>(h_all, ctx, pgW, pgb, pctx, pemb, pgen,
                                      gf);
  k_logits<<<dim3(250, 16), 256, 0, stream>>>(gf, vp16, vpb, outp);
  k_rowsum<<<2048, 256, 0, stream>>>(outp, invs);
  k_final<<<2048, 256, 0, stream>>>(outp, invs, pgen, copyb);
}